// Round 7
// baseline (577.235 us; speedup 1.0000x reference)
//
#include <hip/hip_runtime.h>

#define B_   2
#define S_   2048
#define D_   512
#define H_   8
#define DK_  64
#define DFF_ 2048
#define L_   2
#define BS_  (B_*S_)   // 4096
#define NPROJ 2560     // qr|qi|kr|ki|v concatenated

typedef __attribute__((ext_vector_type(8))) short bfrag;    // 8 bf16 (4 VGPRs)
typedef __attribute__((ext_vector_type(4))) float facc;     // 4 fp32
typedef __attribute__((ext_vector_type(16))) float facc16;  // 16 fp32 (32x32 C/D)
typedef __attribute__((ext_vector_type(4))) int i4v;

__device__ __forceinline__ unsigned short f2b(float f) {
  union { float f; unsigned int u; } c; c.f = f;
  unsigned int u = c.u;
  u += 0x7fffu + ((u >> 16) & 1);    // RNE
  return (unsigned short)(u >> 16);
}

__device__ __forceinline__ float b2f(unsigned short u) {
  union { unsigned u; float f; } c; c.u = (unsigned)u << 16; return c.f;
}

__device__ __forceinline__ unsigned pkb(float hi, float lo) {  // truncating bf16 pack
  union { float f; unsigned u; } a, b; a.f = hi; b.f = lo;
  return (a.u & 0xffff0000u) | (b.u >> 16);
}

__device__ __forceinline__ bfrag asb(i4v x) { union { i4v a; bfrag b; } u; u.a = x; return u.b; }

__device__ __forceinline__ bfrag bneg(bfrag x) {
  union { bfrag b; i4v a; } u; u.b = x;
  u.a.x ^= 0x80008000; u.a.y ^= 0x80008000; u.a.z ^= 0x80008000; u.a.w ^= 0x80008000;
  return u.b;
}

__device__ __forceinline__ void async_copy16(const void* g, void* l) {
  __builtin_amdgcn_global_load_lds((const __attribute__((address_space(1))) void*)g,
                                   (__attribute__((address_space(3))) void*)l,
                                   16, 0, 0);
}

// ---------------- embedding gather: zr fp32 + acat bf16 left half ----------------
__global__ __launch_bounds__(128) void embed_kernel(const int* __restrict__ tokens,
                                                    const float* __restrict__ embed,
                                                    float* __restrict__ zr,
                                                    unsigned short* __restrict__ acat) {
  int row = blockIdx.x;
  int tok = tokens[row];
  float4 v = ((const float4*)(embed + (size_t)tok * D_))[threadIdx.x];
  ((float4*)(zr + (size_t)row * D_))[threadIdx.x] = v;
  ushort4 o; o.x = f2b(v.x); o.y = f2b(v.y); o.z = f2b(v.z); o.w = f2b(v.w);
  *(ushort4*)(acat + (size_t)row * 1024 + threadIdx.x * 4) = o;
}

// ---------------- zi bf16 into acat right half ----------------
__global__ __launch_bounds__(128) void zi_kernel(unsigned short* __restrict__ acat) {
  int row = blockIdx.x;
  int s = row & (S_ - 1);
  int d0 = threadIdx.x * 4;
  const double LN1E4 = 9.210340371976184;
  #pragma unroll
  for (int t = 0; t < 4; ++t) {
    int d = d0 + t;
    int jj = d >> 1;
    double freq = exp(-((double)jj / 256.0) * LN1E4);
    float val = (float)sin((double)s * freq);
    acat[(size_t)row * 1024 + 512 + d] = f2b(val);
  }
}

// ---------------- weight concat+transpose for fused projection ----------------
__global__ __launch_bounds__(256) void wcat_kernel(const float* __restrict__ wqr,
                                                   const float* __restrict__ wqi,
                                                   const float* __restrict__ wkr,
                                                   const float* __restrict__ wki,
                                                   const float* __restrict__ wv,
                                                   unsigned short* __restrict__ dst,
                                                   int KA) {
  __shared__ float tile[64][68];
  const int tid = threadIdx.x;
  const int n0 = blockIdx.x * 64, k0 = blockIdx.y * 64;
  const int p = n0 >> 9, nn0 = n0 & 511;
  const float* src;
  float sign = 1.f;
  bool zero = false;
  if (k0 < 512) {
    const float* tops[5] = {wqr, wqi, wkr, wki, wv};
    src = tops[p];
  } else {
    const float* bots[5] = {wqi, wqr, wki, wkr, nullptr};
    const float sg[5] = {-1.f, 1.f, -1.f, 1.f, 0.f};
    src = bots[p]; sign = sg[p]; zero = (p == 4);
  }
  const int kk0 = k0 & 511;
  #pragma unroll
  for (int i = 0; i < 4; ++i) {
    int lin = tid + i * 256;
    int row = lin >> 4, c4 = (lin & 15) * 4;
    float4 v = make_float4(0.f, 0.f, 0.f, 0.f);
    if (!zero) v = *(const float4*)(src + (size_t)(kk0 + row) * 512 + nn0 + c4);
    *(float4*)&tile[row][c4] = v;
  }
  __syncthreads();
  #pragma unroll
  for (int i = 0; i < 4; ++i) {
    int lin = tid + i * 256;
    int n = lin >> 4, kc4 = (lin & 15) * 4;
    ushort4 o;
    o.x = f2b(sign * tile[kc4 + 0][n]);
    o.y = f2b(sign * tile[kc4 + 1][n]);
    o.z = f2b(sign * tile[kc4 + 2][n]);
    o.w = f2b(sign * tile[kc4 + 3][n]);
    *(ushort4*)(dst + (size_t)(n0 + n) * KA + k0 + kc4) = o;
  }
}

// ---------------- generic weight transpose: fp32 [K,N] -> bf16 [N,K] ----------------
__global__ __launch_bounds__(256) void wtr_kernel(const float* __restrict__ W,
                                                  unsigned short* __restrict__ dst,
                                                  int K, int N) {
  __shared__ float tile[64][68];
  const int tid = threadIdx.x;
  const int n0 = blockIdx.x * 64, k0 = blockIdx.y * 64;
  #pragma unroll
  for (int i = 0; i < 4; ++i) {
    int lin = tid + i * 256;
    int row = lin >> 4, c4 = (lin & 15) * 4;
    *(float4*)&tile[row][c4] = *(const float4*)(W + (size_t)(k0 + row) * N + n0 + c4);
  }
  __syncthreads();
  #pragma unroll
  for (int i = 0; i < 4; ++i) {
    int lin = tid + i * 256;
    int n = lin >> 4, kc4 = (lin & 15) * 4;
    ushort4 o;
    o.x = f2b(tile[kc4 + 0][n]);
    o.y = f2b(tile[kc4 + 1][n]);
    o.z = f2b(tile[kc4 + 2][n]);
    o.w = f2b(tile[kc4 + 3][n]);
    *(ushort4*)(dst + (size_t)(n0 + n) * K + k0 + kc4) = o;
  }
}

// ---------------- bf16 MFMA GEMM (m97 pattern) ----------------
template<int TM>
__global__ __launch_bounds__(256) void gemm_bf16(const unsigned short* __restrict__ A,
                                                 const unsigned short* __restrict__ Bt,
                                                 const float* __restrict__ bias,
                                                 float* __restrict__ outF,
                                                 unsigned short* __restrict__ outB,
                                                 int M, int N, int K, int lda, int relu) {
  constexpr int MT = TM / 32;
  __shared__ short smem[(TM + 128) * 32];
  short* A_s = smem;
  short* B_s = smem + TM * 32;

  const int tid = threadIdx.x;
  const int w = tid >> 6, lane = tid & 63;
  const int col = lane & 15, quad = lane >> 4;
  const int m0 = blockIdx.y * TM, n0 = blockIdx.x * 128;
  const int wrow = (w >> 1) * (TM / 2);
  const int wcol = (w & 1) * 64;

  const int srow = lane >> 2;
  const int skk  = (lane & 3) * 8;

  facc acc[MT][4];
  #pragma unroll
  for (int i = 0; i < MT; ++i)
    #pragma unroll
    for (int j = 0; j < 4; ++j) acc[i][j] = (facc){0.f, 0.f, 0.f, 0.f};

  for (int k0 = 0; k0 < K; k0 += 32) {
    __syncthreads();
    #pragma unroll
    for (int rd = 0; rd < TM / 64; ++rd) {
      int row = rd * 64 + w * 16 + srow;
      async_copy16(A + (size_t)(m0 + row) * lda + k0 + skk, &A_s[row * 32 + skk]);
    }
    #pragma unroll
    for (int rd = 0; rd < 2; ++rd) {
      int row = rd * 64 + w * 16 + srow;
      async_copy16(Bt + (size_t)(n0 + row) * K + k0 + skk, &B_s[row * 32 + skk]);
    }
    __syncthreads();

    bfrag af[MT], bf[4];
    #pragma unroll
    for (int i = 0; i < MT; ++i)
      af[i] = *(const bfrag*)&A_s[(wrow + i * 16 + col) * 32 + quad * 8];
    #pragma unroll
    for (int j = 0; j < 4; ++j)
      bf[j] = *(const bfrag*)&B_s[(wcol + j * 16 + col) * 32 + quad * 8];
    #pragma unroll
    for (int i = 0; i < MT; ++i)
      #pragma unroll
      for (int j = 0; j < 4; ++j)
        acc[i][j] = __builtin_amdgcn_mfma_f32_16x16x32_bf16(af[i], bf[j], acc[i][j], 0, 0, 0);
  }

  #pragma unroll
  for (int i = 0; i < MT; ++i) {
    #pragma unroll
    for (int j = 0; j < 4; ++j) {
      int colIdx = n0 + wcol + j * 16 + col;
      float b = bias ? bias[colIdx] : 0.f;
      #pragma unroll
      for (int r = 0; r < 4; ++r) {
        int rowIdx = m0 + wrow + i * 16 + quad * 4 + r;
        float v = acc[i][j][r] + b;
        if (relu) v = fmaxf(v, 0.f);
        if (outF) outF[(size_t)rowIdx * N + colIdx] = v;
        if (outB) outB[(size_t)rowIdx * N + colIdx] = f2b(v);
      }
    }
  }
}

// ---------------- K/V fragment pre-pack ----------------
// Per (bh, 32-key chunk c): KP block of 6144 elems =
//   kr frags [f=t*2+h][m][8] (2048) | ki frags (2048) | v^T frags [s=(tile*2+kt)*2+h][m][8] (2048)
// so attention A-operand fragment loads are lane-contiguous 16B (fully coalesced).
__global__ __launch_bounds__(256) void prep_kernel(const unsigned short* __restrict__ Q4,
                                                   unsigned short* __restrict__ KP) {
  const int c = blockIdx.x, bh = blockIdx.y;
  const int b = bh >> 3, hd = bh & 7;
  const int hoff = hd * DK_;
  const size_t bS = (size_t)b * S_;
  const int t = threadIdx.x;
  const int m = t & 31, s = t >> 5;            // s = 0..7
  unsigned short* dst = KP + ((size_t)(bh * 64 + c)) * 6144;

  // K: frag elem (f=s, m): src = K[key = c*32+m][d = s*8..s*8+8)
  const unsigned short* src = Q4 + (bS + c * 32 + m) * (size_t)NPROJ + 1024 + hoff + s * 8;
  *(int4*)(dst + s * 256 + m * 8) = *(const int4*)src;                 // kr
  *(int4*)(dst + 2048 + s * 256 + m * 8) = *(const int4*)(src + 512);  // ki

  // V: LDS transpose then frag pack
  __shared__ unsigned short vld[32][72];
  const int key = t >> 3, seg = t & 7;
  *(int4*)&vld[key][seg * 8] =
      *(const int4*)(Q4 + (bS + c * 32 + key) * (size_t)NPROJ + 2048 + hoff + seg * 8);
  __syncthreads();
  const int tile = s >> 2, kt = (s >> 1) & 1, hh = s & 1;
  unsigned short tmp[8];
  #pragma unroll
  for (int j = 0; j < 8; ++j) tmp[j] = vld[kt * 16 + hh * 8 + j][tile * 32 + m];
  *(int4*)(dst + 4096 + s * 256 + m * 8) = *(const int4*)tmp;
}

// ---------------- MFMA complex-hybrid attention, v5 ----------------
// 32x32x16 MFMA, A=K B=Q (C col = q). Fixed softmax max m=0; poly exp.
// grid (S/128, B*H, 4 key-splits); block 256 = 4 waves splitting q (4x32).
// v5: K/V read directly from fragment-order pre-packed KP — every fragment
// load is a coalesced 1KB wave read. NO LDS, NO barriers, NO waitcnts.
__global__ __launch_bounds__(256, 4) void attn_mfma(const unsigned short* __restrict__ Q4,
                                                    const unsigned short* __restrict__ KP,
                                                    unsigned short* __restrict__ po,
                                                    float* __restrict__ pl) {
  const int bh = blockIdx.y;
  const int b = bh >> 3, hd = bh & 7;
  const int hoff = hd * DK_;
  const int ks = blockIdx.z;
  const int tid = threadIdx.x;
  const int w = tid >> 6;
  const int lane = tid & 63;
  const int m = lane & 31;       // C col = q index / A m index
  const int h = lane >> 5;       // half-wave
  const int q0 = blockIdx.x * 128 + w * 32;

  const size_t bS = (size_t)b * S_;

  // Q B-frags (persistent): B[kdim = t*16 + h*8 + j][n=q=m]
  bfrag qrf[4], qif[4], nqrf[4];
  {
    const size_t qrow = (bS + q0 + m) * (size_t)NPROJ + hoff;
    #pragma unroll
    for (int t = 0; t < 4; ++t) {
      qrf[t] = *(const bfrag*)(Q4 + qrow + t * 16 + h * 8);
      qif[t] = *(const bfrag*)(Q4 + qrow + 512 + t * 16 + h * 8);
      nqrf[t] = bneg(qrf[t]);
    }
  }

  facc16 o0 = {}, o1 = {};
  float l = 0.f;
  const float c1 = 0.015625f;   // 1/64
  const float c2 = 0.0375f;     // 0.3/8

  // per-lane fragment base inside a chunk block
  const unsigned short* cb = KP + ((size_t)(bh * 64 + ks * 16)) * 6144 + h * 256 + m * 8;

  for (int ch = 0; ch < 16; ++ch) {
    // ---- fragment loads (each: coalesced global_load_dwordx4) ----
    bfrag krf[4], kif[4], vtf[4];
    #pragma unroll
    for (int t = 0; t < 4; ++t) {
      krf[t] = *(const bfrag*)(cb + t * 512);
      kif[t] = *(const bfrag*)(cb + 2048 + t * 512);
      vtf[t] = *(const bfrag*)(cb + 4096 + t * 512);
    }
    cb += 6144;

    // ---- scores ----
    facc16 sr = {}, si = {};
    #pragma unroll
    for (int t = 0; t < 4; ++t) {
      sr = __builtin_amdgcn_mfma_f32_32x32x16_bf16(krf[t], qrf[t], sr, 0, 0, 0);
      si = __builtin_amdgcn_mfma_f32_32x32x16_bf16(krf[t], qif[t], si, 0, 0, 0);
      sr = __builtin_amdgcn_mfma_f32_32x32x16_bf16(kif[t], qif[t], sr, 0, 0, 0);
      si = __builtin_amdgcn_mfma_f32_32x32x16_bf16(kif[t], nqrf[t], si, 0, 0, 0);
    }

    // ---- hybrid score -> p = exp(x) ~ 1 + x + x^2/2 (|x| <~ 0.2) ----
    float p[16], ssum = 0.f;
    #pragma unroll
    for (int i = 0; i < 16; ++i) {
      float a = sr[i], bb = si[i];
      float d2 = __builtin_fmaf(a, a, __builtin_fmaf(bb, bb, 1e-30f));
      float rs = rsqrtf(d2);
      float x = rs * __builtin_fmaf(c1, d2, c2 * a);
      p[i] = __builtin_fmaf(x, __builtin_fmaf(0.5f, x, 1.f), 1.f);
      ssum += p[i];
    }
    l += ssum;

    // ---- pack P (truncating bf16) + cross-half exchange -> P^T B-frags ----
    unsigned dw[8];
    #pragma unroll
    for (int i = 0; i < 8; ++i) dw[i] = pkb(p[2 * i + 1], p[2 * i]);
    unsigned y1 = (unsigned)__shfl_xor((int)(h ? dw[0] : dw[2]), 32);
    unsigned y2 = (unsigned)__shfl_xor((int)(h ? dw[1] : dw[3]), 32);
    unsigned y3 = (unsigned)__shfl_xor((int)(h ? dw[4] : dw[6]), 32);
    unsigned y4 = (unsigned)__shfl_xor((int)(h ? dw[5] : dw[7]), 32);
    i4v f0 = { (int)(h ? y1 : dw[0]), (int)(h ? y2 : dw[1]),
               (int)(h ? dw[2] : y1), (int)(h ? dw[3] : y2) };
    i4v f1 = { (int)(h ? y3 : dw[4]), (int)(h ? y4 : dw[5]),
               (int)(h ? dw[6] : y3), (int)(h ? dw[7] : y4) };
    bfrag pf0 = asb(f0), pf1 = asb(f1);

    // ---- PV: o^T[d][q] += V^T x P^T ----
    o0 = __builtin_amdgcn_mfma_f32_32x32x16_bf16(vtf[0], pf0, o0, 0, 0, 0);
    o0 = __builtin_amdgcn_mfma_f32_32x32x16_bf16(vtf[1], pf1, o0, 0, 0, 0);
    o1 = __builtin_amdgcn_mfma_f32_32x32x16_bf16(vtf[2], pf0, o1, 0, 0, 0);
    o1 = __builtin_amdgcn_mfma_f32_32x32x16_bf16(vtf[3], pf1, o1, 0, 0, 0);
  }

  // ---- epilogue: write per-split partials (bf16 o, fp32 l) ----
  float l_tot = l + __shfl_xor(l, 32);
  const size_t prow = ((size_t)(bh * 4 + ks)) * S_ + q0 + m;
  #pragma unroll
  for (int tile = 0; tile < 2; ++tile) {
    const facc16& oo = tile ? o1 : o0;
    #pragma unroll
    for (int rg = 0; rg < 4; ++rg) {
      int d0 = tile * 32 + rg * 8 + h * 4;        // d = (reg&3)+8*(reg>>2)+4h
      ushort4 ob;
      ob.x = f2b(oo[4 * rg + 0]);
      ob.y = f2b(oo[4 * rg + 1]);
      ob.z = f2b(oo[4 * rg + 2]);
      ob.w = f2b(oo[4 * rg + 3]);
      *(ushort4*)(po + prow * 64 + d0) = ob;
    }
  }
  if (lane < 32) pl[prow] = l_tot;
}

// ---------------- combine the 4 key-split partials -> ctxb ----------------
__global__ __launch_bounds__(256) void attn_combine(const unsigned short* __restrict__ po,
                                                    const float* __restrict__ pl,
                                                    unsigned short* __restrict__ ctxb) {
  int t = blockIdx.x * 256 + threadIdx.x;      // 262144 threads
  int row = t >> 3;                            // bh*S + q
  int dg = t & 7;
  int bh = row >> 11, q = row & (S_ - 1);
  int b = bh >> 3, hd = bh & 7;
  float acc[8];
  #pragma unroll
  for (int e = 0; e < 8; ++e) acc[e] = 0.f;
  float ls = 0.f;
  #pragma unroll
  for (int ks = 0; ks < 4; ++ks) {
    size_t prow = (((size_t)(bh * 4 + ks)) << 11) + q;
    ls += pl[prow];
    const unsigned short* src = po + prow * 64 + dg * 8;
    ushort4 v0 = *(const ushort4*)src;
    ushort4 v1 = *(const ushort4*)(src + 4);
    acc[0] += b2f(v0.x); acc[1] += b2f(v0.y); acc[2] += b2f(v0.z); acc[3] += b2f(v0.w);
    acc[4] += b2f(v1.x); acc[5] += b2f(v1.y); acc[6] += b2f(v1.z); acc[7] += b2f(v1.w);
  }
  float inv = 1.f / ls;
  unsigned short ob[8];
  #pragma unroll
  for (int e = 0; e < 8; ++e) ob[e] = f2b(acc[e] * inv);
  *(int4*)(ctxb + ((size_t)(b * S_ + q)) * D_ + hd * DK_ + dg * 8) = *(const int4*)ob;
}

// ---------------- layernorm ----------------
__global__ __launch_bounds__(256) void ln_kernel(const float* __restrict__ X,
                                                 const float* __restrict__ R,
                                                 const float* __restrict__ g,
                                                 const float* __restrict__ be,
                                                 float* __restrict__ OutF,
                                                 unsigned short* __restrict__ OutB) {
  const int lane = threadIdx.x & 63;
  const int wv = threadIdx.x >> 6;
  const int row = blockIdx.x * 4 + wv;
  const float* xp = X + (size_t)row * D_;
  const float* rp = R + (size_t)row * D_;
  float x[8];
  float s = 0.f;
  #pragma unroll
  for (int i = 0; i < 8; ++i) {
    int d = i * 64 + lane;
    x[i] = xp[d] + rp[d];
    s += x[i];
  }
  s += __shfl_xor(s, 32); s += __shfl_xor(s, 16); s += __shfl_xor(s, 8);
  s += __shfl_xor(s, 4);  s += __shfl_xor(s, 2);  s += __shfl_xor(s, 1);
  float mu = s * (1.f / 512.f);
  float vs = 0.f;
  #pragma unroll
  for (int i = 0; i < 8; ++i) { float d = x[i] - mu; vs += d * d; }
  vs += __shfl_xor(vs, 32); vs += __shfl_xor(vs, 16); vs += __shfl_xor(vs, 8);
  vs += __shfl_xor(vs, 4);  vs += __shfl_xor(vs, 2);  vs += __shfl_xor(vs, 1);
  float rstd = rsqrtf(vs * (1.f / 512.f) + 1e-5f);
  #pragma unroll
  for (int i = 0; i < 8; ++i) {
    int d = i * 64 + lane;
    float v = (x[i] - mu) * rstd * g[d] + be[d];
    if (OutF) OutF[(size_t)row * D_ + d] = v;
    if (OutB) OutB[(size_t)row * D_ + d] = f2b(v);
  }
}

// ---------------- classifier head ----------------
__global__ __launch_bounds__(256) void head_kernel(const float* __restrict__ Z,
                                                   const float* __restrict__ hw,
                                                   const float* __restrict__ hb,
                                                   float* __restrict__ out) {
  const int lane = threadIdx.x & 63;
  const int wv = threadIdx.x >> 6;
  const int row = blockIdx.x * 4 + wv;
  const float* zp = Z + (size_t)row * D_;
  float a0 = 0.f, a1 = 0.f;
  #pragma unroll
  for (int i = 0; i < 8; ++i) {
    int d = i * 64 + lane;
    float z = zp[d];
    a0 += z * hw[d * 2];
    a1 += z * hw[d * 2 + 1];
  }
  a0 += __shfl_xor(a0, 32); a0 += __shfl_xor(a0, 16); a0 += __shfl_xor(a0, 8);
  a0 += __shfl_xor(a0, 4);  a0 += __shfl_xor(a0, 2);  a0 += __shfl_xor(a0, 1);
  a1 += __shfl_xor(a1, 32); a1 += __shfl_xor(a1, 16); a1 += __shfl_xor(a1, 8);
  a1 += __shfl_xor(a1, 4);  a1 += __shfl_xor(a1, 2);  a1 += __shfl_xor(a1, 1);
  if (lane == 0) {
    out[row * 2]     = a0 + hb[0];
    out[row * 2 + 1] = a1 + hb[1];
  }
}

extern "C" void kernel_launch(void* const* d_in, const int* in_sizes, int n_in,
                              void* d_out, int out_size, void* d_ws, size_t ws_size,
                              hipStream_t stream) {
  const int*   tokens = (const int*)  d_in[0];
  const float* embed  = (const float*)d_in[1];
  const float* Wqr = (const float*)d_in[2];
  const float* Wqi = (const float*)d_in[3];
  const float* Wkr = (const float*)d_in[4];
  const float* Wki = (const float*)d_in[5];
  const float* Wv  = (const float*)d_in[6];
  const float* Wo  = (const float*)d_in[7];
  const float* bo  = (const float*)d_in[8];
  const float* W1  = (const float*)d_in[9];
  const float* b1  = (const float*)d_in[10];
  const float* W2  = (const float*)d_in[11];
  const float* b2  = (const float*)d_in[12];
  const float* g1  = (const float*)d_in[13];
  const float* be1 = (const float*)d_in[14];
  const float* g2  = (const float*)d_in[15];
  const float* be2 = (const float*)d_in[16];
  const float* hw  = (const float*)d_in[17];
  const float* hb  = (const float*)d_in[18];
  float* out = (float*)d_out;

  char* p = (char*)d_ws;
  float* zr = (float*)p;             p += (size_t)BS_ * D_ * 4;
  unsigned short* acat = (unsigned short*)p;
  unsigned short* zrb  = acat;       p += (size_t)BS_ * 1024 * 2;
  unsigned short* Q4   = (unsigned short*)p;
  unsigned short* ffb  = Q4;         p += (size_t)BS_ * NPROJ * 2;
  unsigned short* KP   = (unsigned short*)p; p += (size_t)16 * 64 * 6144 * 2; // 12.6 MB
  unsigned short* ctxb = (unsigned short*)p; p += (size_t)BS_ * D_ * 2;
  float* hbuf = (float*)p;           p += (size_t)BS_ * D_ * 4;
  float* z1   = (float*)p;           p += (size_t)BS_ * D_ * 4;
  unsigned short* z1b = (unsigned short*)p;  p += (size_t)BS_ * D_ * 2;
  unsigned short* wsc = (unsigned short*)p;  p += (size_t)NPROJ * 1024 * 2;

  // attention partials alias regions dead during attention:
  //   po bf16 [16 bh][4 ks][2048 q][64 d] = 16.78 MB -> hbuf+z1(+start of z1b)
  //   pl fp32 [16*4*2048] = 0.5 MB -> wsc
  unsigned short* po = (unsigned short*)hbuf;
  float* pl = (float*)wsc;

  embed_kernel<<<BS_, 128, 0, stream>>>(tokens, embed, zr, acat);
  zi_kernel<<<BS_, 128, 0, stream>>>(acat);

  for (int l = 0; l < L_; ++l) {
    const float* wqr = Wqr + (size_t)l * D_ * D_;
    const float* wqi = Wqi + (size_t)l * D_ * D_;
    const float* wkr = Wkr + (size_t)l * D_ * D_;
    const float* wki = Wki + (size_t)l * D_ * D_;
    const float* wv  = Wv  + (size_t)l * D_ * D_;
    const float* wo  = Wo  + (size_t)l * D_ * D_;
    const float* w1  = W1  + (size_t)l * D_ * DFF_;
    const float* w2  = W2  + (size_t)l * DFF_ * D_;

    const int KA = (l == 0) ? 1024 : 512;
    const unsigned short* Aproj = (l == 0) ? acat : zrb;

    wcat_kernel<<<dim3(NPROJ / 64, KA / 64), 256, 0, stream>>>(wqr, wqi, wkr, wki, wv, wsc, KA);
    gemm_bf16<128><<<dim3(NPROJ / 128, BS_ / 128), 256, 0, stream>>>(
        Aproj, wsc, nullptr, nullptr, Q4, BS_, NPROJ, KA, KA, 0);

    prep_kernel<<<dim3(64, 16), 256, 0, stream>>>(Q4, KP);
    attn_mfma<<<dim3(S_ / 128, B_ * H_, 4), 256, 0, stream>>>(Q4, KP, po, pl);
    attn_combine<<<1024, 256, 0, stream>>>(po, pl, ctxb);

    wtr_kernel<<<dim3(D_ / 64, D_ / 64), 256, 0, stream>>>(wo, wsc, D_, D_);
    gemm_bf16<64><<<dim3(D_ / 128, BS_ / 64), 256, 0, stream>>>(
        ctxb, wsc, bo + l * D_, hbuf, nullptr, BS_, D_, D_, D_, 0);
    ln_kernel<<<BS_ / 4, 256, 0, stream>>>(zr, hbuf, g1 + l * D_, be1 + l * D_, z1, z1b);

    wtr_kernel<<<dim3(DFF_ / 64, D_ / 64), 256, 0, stream>>>(w1, wsc, D_, DFF_);
    gemm_bf16<128><<<dim3(DFF_ / 128, BS_ / 128), 256, 0, stream>>>(
        z1b, wsc, b1 + l * DFF_, nullptr, ffb, BS_, DFF_, D_, D_, 1);
    wtr_kernel<<<dim3(D_ / 64, DFF_ / 64), 256, 0, stream>>>(w2, wsc, DFF_, D_);
    gemm_bf16<64><<<dim3(D_ / 128, BS_ / 64), 256, 0, stream>>>(
        ffb, wsc, b2 + l * D_, hbuf, nullptr, BS_, D_, DFF_, DFF_, 0);
    ln_kernel<<<BS_ / 4, 256, 0, stream>>>(z1, hbuf, g2 + l * D_, be2 + l * D_, zr, zrb);
  }

  head_kernel<<<BS_ / 4, 256, 0, stream>>>(zr, hw, hb, out);
}

// Round 8
// 545.633 us; speedup vs baseline: 1.0579x; 1.0579x over previous
//
#include <hip/hip_runtime.h>

#define B_   2
#define S_   2048
#define D_   512
#define H_   8
#define DK_  64
#define DFF_ 2048
#define L_   2
#define BS_  (B_*S_)   // 4096
#define NPROJ 2560     // qr|qi|kr|ki|v concatenated

typedef __attribute__((ext_vector_type(8))) short bfrag;    // 8 bf16 (4 VGPRs)
typedef __attribute__((ext_vector_type(4))) float facc;     // 4 fp32
typedef __attribute__((ext_vector_type(16))) float facc16;  // 16 fp32 (32x32 C/D)
typedef __attribute__((ext_vector_type(4))) int i4v;

__device__ __forceinline__ unsigned short f2b(float f) {
  union { float f; unsigned int u; } c; c.f = f;
  unsigned int u = c.u;
  u += 0x7fffu + ((u >> 16) & 1);    // RNE
  return (unsigned short)(u >> 16);
}

__device__ __forceinline__ float b2f(unsigned short u) {
  union { unsigned u; float f; } c; c.u = (unsigned)u << 16; return c.f;
}

__device__ __forceinline__ unsigned pkb(float hi, float lo) {  // truncating bf16 pack
  union { float f; unsigned u; } a, b; a.f = hi; b.f = lo;
  return (a.u & 0xffff0000u) | (b.u >> 16);
}

__device__ __forceinline__ bfrag asb(i4v x) { union { i4v a; bfrag b; } u; u.a = x; return u.b; }

__device__ __forceinline__ bfrag bneg(bfrag x) {
  union { bfrag b; i4v a; } u; u.b = x;
  u.a.x ^= 0x80008000; u.a.y ^= 0x80008000; u.a.z ^= 0x80008000; u.a.w ^= 0x80008000;
  return u.b;
}

__device__ __forceinline__ void async_copy16(const void* g, void* l) {
  __builtin_amdgcn_global_load_lds((const __attribute__((address_space(1))) void*)g,
                                   (__attribute__((address_space(3))) void*)l,
                                   16, 0, 0);
}

// ---------------- fused embedding gather + positional zi ----------------
__global__ __launch_bounds__(128) void embed_zi_kernel(const int* __restrict__ tokens,
                                                       const float* __restrict__ embed,
                                                       float* __restrict__ zr,
                                                       unsigned short* __restrict__ acat) {
  int row = blockIdx.x;
  int tok = tokens[row];
  float4 v = ((const float4*)(embed + (size_t)tok * D_))[threadIdx.x];
  ((float4*)(zr + (size_t)row * D_))[threadIdx.x] = v;
  ushort4 o; o.x = f2b(v.x); o.y = f2b(v.y); o.z = f2b(v.z); o.w = f2b(v.w);
  *(ushort4*)(acat + (size_t)row * 1024 + threadIdx.x * 4) = o;

  int s = row & (S_ - 1);
  int d0 = threadIdx.x * 4;
  const double LN1E4 = 9.210340371976184;
  #pragma unroll
  for (int t = 0; t < 4; ++t) {
    int d = d0 + t;
    int jj = d >> 1;
    double freq = exp(-((double)jj / 256.0) * LN1E4);
    float val = (float)sin((double)s * freq);
    acat[(size_t)row * 1024 + 512 + d] = f2b(val);
  }
}

// ---------------- batched weight concat+transpose (both layers) ----------------
__global__ __launch_bounds__(256) void wcat_all(const float* __restrict__ Wqr,
                                                const float* __restrict__ Wqi,
                                                const float* __restrict__ Wkr,
                                                const float* __restrict__ Wki,
                                                const float* __restrict__ Wv,
                                                unsigned short* __restrict__ dst0,
                                                unsigned short* __restrict__ dst1) {
  __shared__ float tile[64][68];
  const int l = blockIdx.z;
  const int KA = l ? 512 : 1024;
  const int k0 = blockIdx.y * 64;
  if (k0 >= KA) return;
  unsigned short* dst = l ? dst1 : dst0;
  const size_t woff = (size_t)l * D_ * D_;
  const float* wqr = Wqr + woff;
  const float* wqi = Wqi + woff;
  const float* wkr = Wkr + woff;
  const float* wki = Wki + woff;
  const float* wv  = Wv  + woff;

  const int tid = threadIdx.x;
  const int n0 = blockIdx.x * 64;
  const int p = n0 >> 9, nn0 = n0 & 511;
  const float* src;
  float sign = 1.f;
  bool zero = false;
  if (k0 < 512) {
    const float* tops[5] = {wqr, wqi, wkr, wki, wv};
    src = tops[p];
  } else {
    const float* bots[5] = {wqi, wqr, wki, wkr, nullptr};
    const float sg[5] = {-1.f, 1.f, -1.f, 1.f, 0.f};
    src = bots[p]; sign = sg[p]; zero = (p == 4);
  }
  const int kk0 = k0 & 511;
  #pragma unroll
  for (int i = 0; i < 4; ++i) {
    int lin = tid + i * 256;
    int row = lin >> 4, c4 = (lin & 15) * 4;
    float4 v = make_float4(0.f, 0.f, 0.f, 0.f);
    if (!zero) v = *(const float4*)(src + (size_t)(kk0 + row) * 512 + nn0 + c4);
    *(float4*)&tile[row][c4] = v;
  }
  __syncthreads();
  #pragma unroll
  for (int i = 0; i < 4; ++i) {
    int lin = tid + i * 256;
    int n = lin >> 4, kc4 = (lin & 15) * 4;
    ushort4 o;
    o.x = f2b(sign * tile[kc4 + 0][n]);
    o.y = f2b(sign * tile[kc4 + 1][n]);
    o.z = f2b(sign * tile[kc4 + 2][n]);
    o.w = f2b(sign * tile[kc4 + 3][n]);
    *(ushort4*)(dst + (size_t)(n0 + n) * KA + k0 + kc4) = o;
  }
}

// ---------------- batched weight transpose: wo/w1/w2 x both layers ----------------
__global__ __launch_bounds__(256) void wtr_all(const float* __restrict__ Wo,
                                               const float* __restrict__ W1,
                                               const float* __restrict__ W2,
                                               unsigned short* __restrict__ pwo,
                                               unsigned short* __restrict__ pw1,
                                               unsigned short* __restrict__ pw2) {
  __shared__ float tile[64][68];
  const int j = blockIdx.z, l = j & 1;
  const float* src; unsigned short* dst; int K, N;
  if (j < 2)      { src = Wo + (size_t)l * 512 * 512;  dst = pwo + (size_t)l * 512 * 512;  K = 512;  N = 512; }
  else if (j < 4) { src = W1 + (size_t)l * 512 * 2048; dst = pw1 + (size_t)l * 2048 * 512; K = 512;  N = 2048; }
  else            { src = W2 + (size_t)l * 2048 * 512; dst = pw2 + (size_t)l * 512 * 2048; K = 2048; N = 512; }
  const int n0 = blockIdx.x * 64, k0 = blockIdx.y * 64;
  if (n0 >= N || k0 >= K) return;
  const int tid = threadIdx.x;
  #pragma unroll
  for (int i = 0; i < 4; ++i) {
    int lin = tid + i * 256;
    int row = lin >> 4, c4 = (lin & 15) * 4;
    *(float4*)&tile[row][c4] = *(const float4*)(src + (size_t)(k0 + row) * N + n0 + c4);
  }
  __syncthreads();
  #pragma unroll
  for (int i = 0; i < 4; ++i) {
    int lin = tid + i * 256;
    int n = lin >> 4, kc4 = (lin & 15) * 4;
    ushort4 o;
    o.x = f2b(tile[kc4 + 0][n]);
    o.y = f2b(tile[kc4 + 1][n]);
    o.z = f2b(tile[kc4 + 2][n]);
    o.w = f2b(tile[kc4 + 3][n]);
    *(ushort4*)(dst + (size_t)(n0 + n) * K + k0 + kc4) = o;
  }
}

// ---------------- bf16 MFMA GEMM (m97 pattern) ----------------
template<int TM>
__global__ __launch_bounds__(256) void gemm_bf16(const unsigned short* __restrict__ A,
                                                 const unsigned short* __restrict__ Bt,
                                                 const float* __restrict__ bias,
                                                 float* __restrict__ outF,
                                                 unsigned short* __restrict__ outB,
                                                 int M, int N, int K, int lda, int relu) {
  constexpr int MT = TM / 32;
  __shared__ short smem[(TM + 128) * 32];
  short* A_s = smem;
  short* B_s = smem + TM * 32;

  const int tid = threadIdx.x;
  const int w = tid >> 6, lane = tid & 63;
  const int col = lane & 15, quad = lane >> 4;
  const int m0 = blockIdx.y * TM, n0 = blockIdx.x * 128;
  const int wrow = (w >> 1) * (TM / 2);
  const int wcol = (w & 1) * 64;

  const int srow = lane >> 2;
  const int skk  = (lane & 3) * 8;

  facc acc[MT][4];
  #pragma unroll
  for (int i = 0; i < MT; ++i)
    #pragma unroll
    for (int j = 0; j < 4; ++j) acc[i][j] = (facc){0.f, 0.f, 0.f, 0.f};

  for (int k0 = 0; k0 < K; k0 += 32) {
    __syncthreads();
    #pragma unroll
    for (int rd = 0; rd < TM / 64; ++rd) {
      int row = rd * 64 + w * 16 + srow;
      async_copy16(A + (size_t)(m0 + row) * lda + k0 + skk, &A_s[row * 32 + skk]);
    }
    #pragma unroll
    for (int rd = 0; rd < 2; ++rd) {
      int row = rd * 64 + w * 16 + srow;
      async_copy16(Bt + (size_t)(n0 + row) * K + k0 + skk, &B_s[row * 32 + skk]);
    }
    __syncthreads();

    bfrag af[MT], bf[4];
    #pragma unroll
    for (int i = 0; i < MT; ++i)
      af[i] = *(const bfrag*)&A_s[(wrow + i * 16 + col) * 32 + quad * 8];
    #pragma unroll
    for (int j = 0; j < 4; ++j)
      bf[j] = *(const bfrag*)&B_s[(wcol + j * 16 + col) * 32 + quad * 8];
    #pragma unroll
    for (int i = 0; i < MT; ++i)
      #pragma unroll
      for (int j = 0; j < 4; ++j)
        acc[i][j] = __builtin_amdgcn_mfma_f32_16x16x32_bf16(af[i], bf[j], acc[i][j], 0, 0, 0);
  }

  #pragma unroll
  for (int i = 0; i < MT; ++i) {
    #pragma unroll
    for (int j = 0; j < 4; ++j) {
      int colIdx = n0 + wcol + j * 16 + col;
      float b = bias ? bias[colIdx] : 0.f;
      #pragma unroll
      for (int r = 0; r < 4; ++r) {
        int rowIdx = m0 + wrow + i * 16 + quad * 4 + r;
        float v = acc[i][j][r] + b;
        if (relu) v = fmaxf(v, 0.f);
        if (outF) outF[(size_t)rowIdx * N + colIdx] = v;
        if (outB) outB[(size_t)rowIdx * N + colIdx] = f2b(v);
      }
    }
  }
}

// ---------------- V transpose: Q4 cols [2048,2560) -> bf16 [b,h,dk,s] ----------------
__global__ __launch_bounds__(256) void vt_kernel(const unsigned short* __restrict__ Q4,
                                                 unsigned short* __restrict__ vt) {
  __shared__ short tile[64][80];
  const int bh = blockIdx.x;
  const int b = bh >> 3, hd = bh & 7;
  const int s0 = blockIdx.y * 64;
  const int tid = threadIdx.x;
  #pragma unroll
  for (int i = 0; i < 2; ++i) {
    int lin = tid + i * 256;
    int row = lin >> 3;
    int c8 = (lin & 7) * 8;
    *(int4*)&tile[row][c8] =
      *(const int4*)(Q4 + (size_t)(b * S_ + s0 + row) * NPROJ + 2048 + hd * DK_ + c8);
  }
  __syncthreads();
  #pragma unroll
  for (int i = 0; i < 2; ++i) {
    int lin = tid + i * 256;
    int d = lin >> 3;
    int s8 = (lin & 7) * 8;
    short tmp[8];
    #pragma unroll
    for (int t = 0; t < 8; ++t) tmp[t] = tile[s8 + t][d];
    *(int4*)(vt + ((size_t)bh * DK_ + d) * S_ + s0 + s8) = *(const int4*)tmp;
  }
}

// ---------------- MFMA complex-hybrid attention, v6 (R6 core, 8 waves) ----------------
// 32x32x16 MFMA, A=K B=Q (C col = q). Fixed softmax max m=0; poly exp.
// grid (S/256, B*H, 4 key-splits); block 512 = 8 waves splitting q (8x32 rows),
// SHARING one double-buffered 2x12KB staged K/V chunk (32 keys) -> K/V global
// re-read factor halves vs 4-wave blocks. Staging issued by tid<256 only.
__global__ __launch_bounds__(512, 2) void attn_mfma(const unsigned short* __restrict__ Q4,
                                                    const unsigned short* __restrict__ VT,
                                                    unsigned short* __restrict__ po,
                                                    float* __restrict__ pl) {
  __shared__ __align__(16) short smem[12288];   // 2 x (kr 2048 | ki 2048 | vt 2048)

  const int bh = blockIdx.y;
  const int b = bh >> 3, hd = bh & 7;
  const int hoff = hd * DK_;
  const int ks = blockIdx.z;
  const int tid = threadIdx.x;
  const int w = tid >> 6;
  const int lane = tid & 63;
  const int m = lane & 31;       // C col = q index / A m index
  const int h = lane >> 5;       // half-wave
  const int x7 = m & 7;
  const int q0 = blockIdx.x * 256 + w * 32;
  const int kb = ks * 512;

  const size_t bS = (size_t)b * S_;
  const size_t vtbase = (size_t)bh * DK_ * S_;

  // staging indices (threads < 256 only)
  const int skey = tid >> 3, sseg = tid & 7;
  const int sls = sseg ^ (skey & 7);            // XOR bank swizzle (K)
  const int sd = tid >> 2, ssg2 = tid & 3;
  const int sls2 = ssg2 ^ (sd & 3);             // XOR bank swizzle (V)

  // Q B-frags (persistent): B[kdim = t*16 + h*8 + j][n=q=m]
  bfrag qrf[4], qif[4], nqrf[4];
  {
    const size_t qrow = (bS + q0 + m) * (size_t)NPROJ + hoff;
    #pragma unroll
    for (int t = 0; t < 4; ++t) {
      qrf[t] = *(const bfrag*)(Q4 + qrow + t * 16 + h * 8);
      qif[t] = *(const bfrag*)(Q4 + qrow + 512 + t * 16 + h * 8);
      nqrf[t] = bneg(qrf[t]);
    }
  }

  facc16 o0 = {}, o1 = {};
  float l = 0.f;
  const float c1 = 0.015625f;   // 1/64
  const float c2 = 0.0375f;     // 0.3/8

  auto stage = [&](int c0, int buf) {
    if (tid < 256) {
      short* base = smem + buf * 6144;
      const unsigned short* gk = Q4 + (bS + c0 + skey) * (size_t)NPROJ + 1024 + hoff + sls * 8;
      async_copy16(gk, base + tid * 8);                 // kr
      async_copy16(gk + 512, base + 2048 + tid * 8);    // ki
      async_copy16(VT + vtbase + (size_t)sd * S_ + c0 + sls2 * 8,
                   base + 4096 + tid * 8);              // v^T
    }
  };

  stage(kb, 0);

  for (int ch = 0; ch < 16; ++ch) {
    const int cur = ch & 1;
    __builtin_amdgcn_s_waitcnt(0x0F70);          // vmcnt(0): my staging landed
    __syncthreads();                              // all staging visible; prev readers done
    if (ch < 15) stage(kb + (ch + 1) * 32, 1 - cur);

    const short* kr_s = smem + cur * 6144;
    const short* ki_s = kr_s + 2048;
    const short* vt_s = kr_s + 4096;

    // ---- K frags (A-operand): A[m=key][kdim = t*16+h*8+j] ----
    bfrag krf[4], kif[4];
    #pragma unroll
    for (int t = 0; t < 4; ++t) {
      int off = m * 128 + (((2 * t + h) ^ x7) << 4);
      krf[t] = *(const bfrag*)((const char*)kr_s + off);
      kif[t] = *(const bfrag*)((const char*)ki_s + off);
    }
    // ---- V^T frags (A-operand): A[m=d-local][key k = kt*16+h*8+j] ----
    bfrag vtf[4];
    #pragma unroll
    for (int tile = 0; tile < 2; ++tile)
      #pragma unroll
      for (int kt = 0; kt < 2; ++kt)
        vtf[tile * 2 + kt] = *(const bfrag*)((const char*)vt_s +
            (tile * 32 + m) * 64 + (((kt * 2 + h) ^ (m & 3)) << 4));

    // ---- scores ----
    facc16 sr = {}, si = {};
    #pragma unroll
    for (int t = 0; t < 4; ++t) {
      sr = __builtin_amdgcn_mfma_f32_32x32x16_bf16(krf[t], qrf[t], sr, 0, 0, 0);
      si = __builtin_amdgcn_mfma_f32_32x32x16_bf16(krf[t], qif[t], si, 0, 0, 0);
      sr = __builtin_amdgcn_mfma_f32_32x32x16_bf16(kif[t], qif[t], sr, 0, 0, 0);
      si = __builtin_amdgcn_mfma_f32_32x32x16_bf16(kif[t], nqrf[t], si, 0, 0, 0);
    }

    // ---- hybrid score -> p = exp(x) ~ 1 + x + x^2/2 (|x| <~ 0.2) ----
    float p[16], ssum = 0.f;
    #pragma unroll
    for (int i = 0; i < 16; ++i) {
      float a = sr[i], bb = si[i];
      float d2 = __builtin_fmaf(a, a, __builtin_fmaf(bb, bb, 1e-30f));
      float rs = rsqrtf(d2);
      float x = rs * __builtin_fmaf(c1, d2, c2 * a);
      p[i] = __builtin_fmaf(x, __builtin_fmaf(0.5f, x, 1.f), 1.f);
      ssum += p[i];
    }
    l += ssum;

    // ---- pack P (truncating bf16) + cross-half exchange -> P^T B-frags ----
    unsigned dw[8];
    #pragma unroll
    for (int i = 0; i < 8; ++i) dw[i] = pkb(p[2 * i + 1], p[2 * i]);
    unsigned y1 = (unsigned)__shfl_xor((int)(h ? dw[0] : dw[2]), 32);
    unsigned y2 = (unsigned)__shfl_xor((int)(h ? dw[1] : dw[3]), 32);
    unsigned y3 = (unsigned)__shfl_xor((int)(h ? dw[4] : dw[6]), 32);
    unsigned y4 = (unsigned)__shfl_xor((int)(h ? dw[5] : dw[7]), 32);
    i4v f0 = { (int)(h ? y1 : dw[0]), (int)(h ? y2 : dw[1]),
               (int)(h ? dw[2] : y1), (int)(h ? dw[3] : y2) };
    i4v f1 = { (int)(h ? y3 : dw[4]), (int)(h ? y4 : dw[5]),
               (int)(h ? dw[6] : y3), (int)(h ? dw[7] : y4) };
    bfrag pf0 = asb(f0), pf1 = asb(f1);

    // ---- PV: o^T[d][q] += V^T x P^T ----
    o0 = __builtin_amdgcn_mfma_f32_32x32x16_bf16(vtf[0], pf0, o0, 0, 0, 0);
    o0 = __builtin_amdgcn_mfma_f32_32x32x16_bf16(vtf[1], pf1, o0, 0, 0, 0);
    o1 = __builtin_amdgcn_mfma_f32_32x32x16_bf16(vtf[2], pf0, o1, 0, 0, 0);
    o1 = __builtin_amdgcn_mfma_f32_32x32x16_bf16(vtf[3], pf1, o1, 0, 0, 0);
  }

  // ---- epilogue: write per-split partials (bf16 o, fp32 l) ----
  float l_tot = l + __shfl_xor(l, 32);
  const size_t prow = ((size_t)(bh * 4 + ks)) * S_ + q0 + m;
  #pragma unroll
  for (int tile = 0; tile < 2; ++tile) {
    const facc16& oo = tile ? o1 : o0;
    #pragma unroll
    for (int rg = 0; rg < 4; ++rg) {
      int d0 = tile * 32 + rg * 8 + h * 4;        // d = (reg&3)+8*(reg>>2)+4h
      ushort4 ob;
      ob.x = f2b(oo[4 * rg + 0]);
      ob.y = f2b(oo[4 * rg + 1]);
      ob.z = f2b(oo[4 * rg + 2]);
      ob.w = f2b(oo[4 * rg + 3]);
      *(ushort4*)(po + prow * 64 + d0) = ob;
    }
  }
  if (lane < 32) pl[prow] = l_tot;
}

// ---------------- combine the 4 key-split partials -> ctxb ----------------
__global__ __launch_bounds__(256) void attn_combine(const unsigned short* __restrict__ po,
                                                    const float* __restrict__ pl,
                                                    unsigned short* __restrict__ ctxb) {
  int t = blockIdx.x * 256 + threadIdx.x;      // 262144 threads
  int row = t >> 3;                            // bh*S + q
  int dg = t & 7;
  int bh = row >> 11, q = row & (S_ - 1);
  int b = bh >> 3, hd = bh & 7;
  float acc[8];
  #pragma unroll
  for (int e = 0; e < 8; ++e) acc[e] = 0.f;
  float ls = 0.f;
  #pragma unroll
  for (int ks = 0; ks < 4; ++ks) {
    size_t prow = (((size_t)(bh * 4 + ks)) << 11) + q;
    ls += pl[prow];
    const unsigned short* src = po + prow * 64 + dg * 8;
    ushort4 v0 = *(const ushort4*)src;
    ushort4 v1 = *(const ushort4*)(src + 4);
    acc[0] += b2f(v0.x); acc[1] += b2f(v0.y); acc[2] += b2f(v0.z); acc[3] += b2f(v0.w);
    acc[4] += b2f(v1.x); acc[5] += b2f(v1.y); acc[6] += b2f(v1.z); acc[7] += b2f(v1.w);
  }
  float inv = 1.f / ls;
  unsigned short ob[8];
  #pragma unroll
  for (int e = 0; e < 8; ++e) ob[e] = f2b(acc[e] * inv);
  *(int4*)(ctxb + ((size_t)(b * S_ + q)) * D_ + hd * DK_ + dg * 8) = *(const int4*)ob;
}

// ---------------- layernorm ----------------
__global__ __launch_bounds__(256) void ln_kernel(const float* __restrict__ X,
                                                 const float* __restrict__ R,
                                                 const float* __restrict__ g,
                                                 const float* __restrict__ be,
                                                 float* __restrict__ OutF,
                                                 unsigned short* __restrict__ OutB) {
  const int lane = threadIdx.x & 63;
  const int wv = threadIdx.x >> 6;
  const int row = blockIdx.x * 4 + wv;
  const float* xp = X + (size_t)row * D_;
  const float* rp = R + (size_t)row * D_;
  float x[8];
  float s = 0.f;
  #pragma unroll
  for (int i = 0; i < 8; ++i) {
    int d = i * 64 + lane;
    x[i] = xp[d] + rp[d];
    s += x[i];
  }
  s += __shfl_xor(s, 32); s += __shfl_xor(s, 16); s += __shfl_xor(s, 8);
  s += __shfl_xor(s, 4);  s += __shfl_xor(s, 2);  s += __shfl_xor(s, 1);
  float mu = s * (1.f / 512.f);
  float vs = 0.f;
  #pragma unroll
  for (int i = 0; i < 8; ++i) { float d = x[i] - mu; vs += d * d; }
  vs += __shfl_xor(vs, 32); vs += __shfl_xor(vs, 16); vs += __shfl_xor(vs, 8);
  vs += __shfl_xor(vs, 4);  vs += __shfl_xor(vs, 2);  vs += __shfl_xor(vs, 1);
  float rstd = rsqrtf(vs * (1.f / 512.f) + 1e-5f);
  #pragma unroll
  for (int i = 0; i < 8; ++i) {
    int d = i * 64 + lane;
    float v = (x[i] - mu) * rstd * g[d] + be[d];
    if (OutF) OutF[(size_t)row * D_ + d] = v;
    if (OutB) OutB[(size_t)row * D_ + d] = f2b(v);
  }
}

// ---------------- classifier head ----------------
__global__ __launch_bounds__(256) void head_kernel(const float* __restrict__ Z,
                                                   const float* __restrict__ hw,
                                                   const float* __restrict__ hb,
                                                   float* __restrict__ out) {
  const int lane = threadIdx.x & 63;
  const int wv = threadIdx.x >> 6;
  const int row = blockIdx.x * 4 + wv;
  const float* zp = Z + (size_t)row * D_;
  float a0 = 0.f, a1 = 0.f;
  #pragma unroll
  for (int i = 0; i < 8; ++i) {
    int d = i * 64 + lane;
    float z = zp[d];
    a0 += z * hw[d * 2];
    a1 += z * hw[d * 2 + 1];
  }
  a0 += __shfl_xor(a0, 32); a0 += __shfl_xor(a0, 16); a0 += __shfl_xor(a0, 8);
  a0 += __shfl_xor(a0, 4);  a0 += __shfl_xor(a0, 2);  a0 += __shfl_xor(a0, 1);
  a1 += __shfl_xor(a1, 32); a1 += __shfl_xor(a1, 16); a1 += __shfl_xor(a1, 8);
  a1 += __shfl_xor(a1, 4);  a1 += __shfl_xor(a1, 2);  a1 += __shfl_xor(a1, 1);
  if (lane == 0) {
    out[row * 2]     = a0 + hb[0];
    out[row * 2 + 1] = a1 + hb[1];
  }
}

extern "C" void kernel_launch(void* const* d_in, const int* in_sizes, int n_in,
                              void* d_out, int out_size, void* d_ws, size_t ws_size,
                              hipStream_t stream) {
  const int*   tokens = (const int*)  d_in[0];
  const float* embed  = (const float*)d_in[1];
  const float* Wqr = (const float*)d_in[2];
  const float* Wqi = (const float*)d_in[3];
  const float* Wkr = (const float*)d_in[4];
  const float* Wki = (const float*)d_in[5];
  const float* Wv  = (const float*)d_in[6];
  const float* Wo  = (const float*)d_in[7];
  const float* bo  = (const float*)d_in[8];
  const float* W1  = (const float*)d_in[9];
  const float* b1  = (const float*)d_in[10];
  const float* W2  = (const float*)d_in[11];
  const float* b2  = (const float*)d_in[12];
  const float* g1  = (const float*)d_in[13];
  const float* be1 = (const float*)d_in[14];
  const float* g2  = (const float*)d_in[15];
  const float* be2 = (const float*)d_in[16];
  const float* hw  = (const float*)d_in[17];
  const float* hb  = (const float*)d_in[18];
  float* out = (float*)d_out;

  char* p = (char*)d_ws;
  float* zr = (float*)p;             p += (size_t)BS_ * D_ * 4;           // 8 MB
  unsigned short* acat = (unsigned short*)p;
  unsigned short* zrb  = acat;       p += (size_t)BS_ * 1024 * 2;         // 8 MB
  unsigned short* Q4   = (unsigned short*)p;
  unsigned short* ffb  = Q4;         p += (size_t)BS_ * NPROJ * 2;        // 20 MB
  unsigned short* VT   = (unsigned short*)p; p += (size_t)B_*H_*DK_*S_*2; // 4 MB
  unsigned short* ctxb = (unsigned short*)p; p += (size_t)BS_ * D_ * 2;   // 4 MB
  float* hbuf = (float*)p;           p += (size_t)BS_ * D_ * 4;           // 8 MB
  float* z1   = (float*)p;           p += (size_t)BS_ * D_ * 4;           // 8 MB  (contiguous after hbuf)
  unsigned short* z1b = (unsigned short*)p;  p += (size_t)BS_ * D_ * 2;   // 4 MB  (contiguous after z1)
  unsigned short* pw_proj0 = (unsigned short*)p; p += (size_t)NPROJ * 1024 * 2; // 5 MB
  unsigned short* pw_proj1 = (unsigned short*)p; p += (size_t)NPROJ * 512 * 2;  // 2.5 MB
  unsigned short* pw_wo = (unsigned short*)p;    p += (size_t)2 * 512 * 512 * 2;   // 1 MB
  unsigned short* pw_w1 = (unsigned short*)p;    p += (size_t)2 * 2048 * 512 * 2;  // 4 MB
  unsigned short* pw_w2 = (unsigned short*)p;    p += (size_t)2 * 512 * 2048 * 2;  // 4 MB
  float* pl = (float*)p;             p += (size_t)16 * 4 * S_ * 4;        // 0.5 MB

  // po bf16 [16 bh][4 ks][2048 q][64 d] = 16.78 MB -> aliases hbuf+z1+start of z1b
  // (all dead during attention; combine reads po before the Wo GEMM rewrites hbuf)
  unsigned short* po = (unsigned short*)hbuf;

  embed_zi_kernel<<<BS_, 128, 0, stream>>>(tokens, embed, zr, acat);
  wcat_all<<<dim3(NPROJ / 64, 16, 2), 256, 0, stream>>>(Wqr, Wqi, Wkr, Wki, Wv,
                                                        pw_proj0, pw_proj1);
  wtr_all<<<dim3(32, 32, 6), 256, 0, stream>>>(Wo, W1, W2, pw_wo, pw_w1, pw_w2);

  for (int l = 0; l < L_; ++l) {
    const int KA = (l == 0) ? 1024 : 512;
    const unsigned short* Aproj = (l == 0) ? acat : zrb;
    const unsigned short* Wproj = (l == 0) ? pw_proj0 : pw_proj1;

    gemm_bf16<128><<<dim3(NPROJ / 128, BS_ / 128), 256, 0, stream>>>(
        Aproj, Wproj, nullptr, nullptr, Q4, BS_, NPROJ, KA, KA, 0);

    vt_kernel<<<dim3(B_ * H_, S_ / 64), 256, 0, stream>>>(Q4, VT);
    attn_mfma<<<dim3(S_ / 256, B_ * H_, 4), 512, 0, stream>>>(Q4, VT, po, pl);
    attn_combine<<<1024, 256, 0, stream>>>(po, pl, ctxb);

    gemm_bf16<64><<<dim3(D_ / 128, BS_ / 64), 256, 0, stream>>>(
        ctxb, pw_wo + (size_t)l * 512 * 512, bo + l * D_, hbuf, nullptr,
        BS_, D_, D_, D_, 0);
    ln_kernel<<<BS_ / 4, 256, 0, stream>>>(zr, hbuf, g1 + l * D_, be1 + l * D_, z1, z1b);

    gemm_bf16<128><<<dim3(DFF_ / 128, BS_ / 128), 256, 0, stream>>>(
        z1b, pw_w1 + (size_t)l * 2048 * 512, b1 + l * DFF_, nullptr, ffb,
        BS_, DFF_, D_, D_, 1);
    gemm_bf16<64><<<dim3(D_ / 128, BS_ / 64), 256, 0, stream>>>(
        ffb, pw_w2 + (size_t)l * 512 * 2048, b2 + l * D_, hbuf, nullptr,
        BS_, D_, DFF_, DFF_, 0);
    ln_kernel<<<BS_ / 4, 256, 0, stream>>>(z1, hbuf, g2 + l * D_, be2 + l * D_, zr, zrb);
  }

  head_kernel<<<BS_ / 4, 256, 0, stream>>>(zr, hw, hb, out);
}